// Round 13
// baseline (198.727 us; speedup 1.0000x reference)
//
#include <hip/hip_runtime.h>
#include <stdint.h>

#define NIMG 4
#define PTOT 8400
#define NCLS 80
#define NW   132            // 64-bit words per removed-bitmask row (ceil(8400/64))
#define DMAX 3              // static upper bound on label distance (dynamic check tightens)
#define SORT_T 1024         // sort threads per block
#define SORT_E 9            // elements per thread
#define NPAD_S (SORT_T * SORT_E)  // 9216 >= 8400
#define ECAP 65536          // edge buffer capacity per image (expected ~150)
#define ERCAP 1024          // register-resident edge fast path (16 slots x 64 lanes)
#define PTILE 512           // LDS box tile for pair enumeration
#define NMS_THR_C 0.65f
#define SCORE_THR_C 0.01f

static __device__ __forceinline__ float sigmoidf_(float x) {
  return 1.0f / (1.0f + expf(-x));
}
// order-preserving float->uint encoding for atomicMax/Min
static __device__ __forceinline__ unsigned enc_f(float f) {
  unsigned u = __float_as_uint(f);
  return (u >> 31) ? ~u : (u | 0x80000000u);
}
static __device__ __forceinline__ float dec_f(unsigned e) {
  return (e >> 31) ? __uint_as_float(e ^ 0x80000000u) : __uint_as_float(~e);
}

__global__ void k_init(unsigned* gmax, unsigned* gmin, uint64_t* flags, int* nvalid,
                       int* lhist, int* ecnt) {
  int t = blockIdx.x * 256 + threadIdx.x;
  int NT = gridDim.x * 256;
  for (int k = t; k < NIMG * NW; k += NT) flags[k] = 0ull;     // 4.2 KB
  for (int k = t; k < NIMG * NCLS; k += NT) lhist[k] = 0;
  if (t < NIMG) { gmax[t] = 0u; gmin[t] = 0xFFFFFFFFu; nvalid[t] = 0; ecnt[t] = 0; }
}

// ---------------- decode: 4 threads/point x 20 classes; sigmoid argmax + box decode
__global__ __launch_bounds__(256) void k_decode(
    const float* __restrict__ cls0, const float* __restrict__ cls1, const float* __restrict__ cls2,
    const float* __restrict__ reg0, const float* __restrict__ reg1, const float* __restrict__ reg2,
    const float* __restrict__ obj0, const float* __restrict__ obj1, const float* __restrict__ obj2,
    float* __restrict__ score, int* __restrict__ label, float* __restrict__ boxes,
    unsigned* __restrict__ gmax, unsigned* __restrict__ gmin, int* __restrict__ lhist)
{
  int t = blockIdx.x * 256 + threadIdx.x;   // 525 blocks * 256 == NIMG*PTOT*4 exactly
  int n = t / (PTOT * 4);
  int rem = t - n * (PTOT * 4);
  int p = rem >> 2, q = rem & 3;            // 4 consecutive lanes share one point
  const float* cb; const float* rb; const float* ob;
  int HW, W, pl; float s;
  if (p < 6400)      { cb = cls0; rb = reg0; ob = obj0; HW = 6400; W = 80; pl = p;        s = 8.f;  }
  else if (p < 8000) { cb = cls1; rb = reg1; ob = obj1; HW = 1600; W = 40; pl = p - 6400; s = 16.f; }
  else               { cb = cls2; rb = reg2; ob = obj2; HW = 400;  W = 20; pl = p - 8000; s = 32.f; }

  // partial argmax over 20 sigmoid(cls) values (first-max-wins within quarter)
  const float* cp = cb + (size_t)n * NCLS * HW + pl;
  float best = -1.0f; int bi = 0;
#pragma unroll
  for (int cc = 0; cc < 20; ++cc) {
    int c = q * 20 + cc;
    float v = sigmoidf_(cp[(size_t)c * HW]);
    if (v > best) { best = v; bi = c; }
  }
  // merge quarters; lower class index wins ties (replicates jnp.argmax first-max)
  {
    float ob_ = __shfl_xor(best, 1, 64); int oi = __shfl_xor(bi, 1, 64);
    float bl, bh; int il, ih;
    if ((q & 1) == 0) { bl = best; il = bi; bh = ob_; ih = oi; }
    else              { bl = ob_;  il = oi; bh = best; ih = bi; }
    if (bh > bl) { best = bh; bi = ih; } else { best = bl; bi = il; }
  }
  {
    float ob_ = __shfl_xor(best, 2, 64); int oi = __shfl_xor(bi, 2, 64);
    float bl, bh; int il, ih;
    if ((q & 2) == 0) { bl = best; il = bi; bh = ob_; ih = oi; }
    else              { bl = ob_;  il = oi; bh = best; ih = bi; }
    if (bh > bl) { best = bh; bi = ih; } else { best = bl; bi = il; }
  }

  float m = -3.4e38f, m2 = 3.4e38f;
  if (q == 0) {
    float osg = sigmoidf_(ob[(size_t)n * HW + pl]);
    float sc = best * osg;
    const float* rp = rb + (size_t)n * 4 * HW + pl;
    float rx = rp[0], ry = rp[(size_t)HW], rw = rp[(size_t)2 * HW], rh = rp[(size_t)3 * HW];
    int ph = pl / W, pw = pl - ph * W;
    float cx = rx * s + (float)pw * s, cy = ry * s + (float)ph * s;
    float bw = expf(rw) * s, bh2 = expf(rh) * s;
    float x1 = cx - bw * 0.5f, y1 = cy - bh2 * 0.5f;
    float x2 = cx + bw * 0.5f, y2 = cy + bh2 * 0.5f;
    int g = n * PTOT + p;
    score[g] = sc;
    label[g] = bi;
    atomicAdd(&lhist[n * NCLS + bi], 1);
    float* bx = boxes + (size_t)g * 4;
    bx[0] = x1; bx[1] = y1; bx[2] = x2; bx[3] = y2;
    m = fmaxf(x2, y2);        // max coord (x2>x1, y2>y1 always: bw,bh>0)
    m2 = fminf(x1, y1);       // min coord
  }
  // wave reduces (wave is single-image: 33600 % 64 == 0)
  for (int o = 32; o; o >>= 1) {
    m = fmaxf(m, __shfl_xor(m, o, 64));
    m2 = fminf(m2, __shfl_xor(m2, o, 64));
  }
  if ((threadIdx.x & 63) == 0) {
    atomicMax(&gmax[n], enc_f(m));
    atomicMin(&gmin[n], enc_f(m2));
  }
}

// ---------------- per-image stable LSD radix sort (8 x 4-bit) -> rank permutation
// 1024 threads x 9 elements: short cursor chains, 16 waves of latency hiding.
// Same stable permutation as verified R8/R10 (flat slot order f = d*T + t,
// within-thread order preserved). Static LDS: 92,224 B (gfx950 allows 160 KB/WG).
__global__ __launch_bounds__(SORT_T) void k_sort(
    const float* __restrict__ score, int* __restrict__ rank,
    const int* __restrict__ lhist, int* __restrict__ bstart, int* __restrict__ cursor)
{
  __shared__ uint32_t A[NPAD_S];          // 36,864 B keys
  __shared__ uint16_t Pp[NPAD_S];         // 18,432 B payload (orig index)
  __shared__ uint16_t hist[16 * SORT_T];  // 32,768 B (slot f = d*1024+t)
  __shared__ uint32_t part[SORT_T];       // 4,096 B chunk exclusive prefixes
  __shared__ uint32_t wsum[16];           // 64 B wave totals
  int n = blockIdx.x, t = threadIdx.x;
  const float* sc = score + (size_t)n * PTOT;
  for (int i = t; i < PTOT; i += SORT_T) {
    float v = sc[i];
    float key = (v >= SCORE_THR_C) ? v : -1.0f;
    A[i] = ~enc_f(key);
    Pp[i] = (uint16_t)i;
  }
  for (int i = PTOT + t; i < NPAD_S; i += SORT_T) {
    A[i] = 0xFFFFFFFFu;               // sorts strictly last
    Pp[i] = (uint16_t)i;
  }
  __syncthreads();
  const int base0 = t * SORT_E;       // 1024*9 == NPAD_S
  const int w = t >> 6, wl = t & 63;  // wave id, lane id
  for (int pass = 0; pass < 8; ++pass) {
    const int sh = pass * 4;
    uint32_t k[SORT_E]; uint16_t p[SORT_E];
#pragma unroll
    for (int e = 0; e < SORT_E; ++e) { k[e] = A[base0 + e]; p[e] = Pp[base0 + e]; }
    // count phase: 16 digit counters packed 8-bit into two u64 (no LDS rmw)
    uint64_t c0 = 0, c1 = 0;
#pragma unroll
    for (int e = 0; e < SORT_E; ++e) {
      uint32_t d = (k[e] >> sh) & 15u;
      uint64_t inc = 1ull << ((d & 7u) << 3);
      if (d < 8) c0 += inc; else c1 += inc;
    }
#pragma unroll
    for (int d = 0; d < 16; ++d) {
      uint32_t cnt = (uint32_t)(((d < 8) ? (c0 >> (d * 8)) : (c1 >> ((d - 8) * 8))) & 0xFFull);
      hist[d * SORT_T + t] = (uint16_t)cnt;
    }
    __syncthreads();
    // level-1: exclusive scan of 16 contiguous slots per thread (flat slot order)
    uint32_t s = 0;
#pragma unroll
    for (int qq = 0; qq < 16; ++qq) {
      int f = t * 16 + qq;
      uint32_t h = hist[f];
      hist[f] = (uint16_t)s;
      s += h;
    }
    // wave inclusive shfl scan over chunk totals
    uint32_t v = s;
#pragma unroll
    for (int off = 1; off < 64; off <<= 1) {
      uint32_t u = __shfl_up(v, off, 64);
      if (wl >= off) v += u;
    }
    if (wl == 63) wsum[w] = v;
    __syncthreads();
    uint32_t wpre = 0;
#pragma unroll
    for (int wv = 0; wv < 16; ++wv) wpre += (wv < w) ? wsum[wv] : 0;
    part[t] = v - s + wpre;           // exclusive prefix of chunk t
    __syncthreads();
    // scatter: pos = hist[f] + part[f>>4] + within-thread running count (packed regs)
    uint64_t cc0 = 0, cc1 = 0;
#pragma unroll
    for (int e = 0; e < SORT_E; ++e) {
      uint32_t d = (k[e] >> sh) & 15u;
      int f = d * SORT_T + t;
      uint32_t within = (uint32_t)(((d < 8) ? (cc0 >> ((d & 7u) << 3))
                                            : (cc1 >> ((d & 7u) << 3))) & 0xFFull);
      uint32_t pos = (uint32_t)hist[f] + part[f >> 4] + within;
      A[pos] = k[e];
      Pp[pos] = p[e];
      uint64_t inc = 1ull << ((d & 7u) << 3);
      if (d < 8) cc0 += inc; else cc1 += inc;
    }
    __syncthreads();
  }
  for (int pos = t; pos < PTOT; pos += SORT_T)   // pads occupy pos >= PTOT only
    rank[(size_t)n * PTOT + Pp[pos]] = pos;
  // label-bucket exclusive scan (fold of old k_bscan)
  if (t == 0) {
    int acc = 0;
    for (int L = 0; L < NCLS; ++L) { bstart[n * (NCLS + 1) + L] = acc; acc += lhist[n * NCLS + L]; }
    bstart[n * (NCLS + 1) + NCLS] = acc;
  }
  __syncthreads();
  if (t < NCLS) cursor[n * NCLS + t] = bstart[n * (NCLS + 1) + t];
}

// ---------------- scatter into sorted order + shifted boxes/areas + nvalid + bucket fill
__global__ __launch_bounds__(256) void k_scatter(
    const float* __restrict__ score, const int* __restrict__ label, const float* __restrict__ boxes,
    const unsigned* __restrict__ gmax, const int* __restrict__ rank, int* __restrict__ nvalid,
    float* __restrict__ s_score, int* __restrict__ s_label,
    float* __restrict__ s_box, float* __restrict__ s_sbox, float* __restrict__ s_area,
    int* __restrict__ cursor, int* __restrict__ bidx)
{
  int n = blockIdx.y;
  int i = blockIdx.x * 256 + threadIdx.x;
  if (i >= PTOT) return;
  const float* sc = score + (size_t)n * PTOT;
  float v = sc[i];
  bool valid = (v >= SCORE_THR_C);
  unsigned long long bal = __ballot(valid);
  if ((threadIdx.x & 63) == 0) atomicAdd(&nvalid[n], (int)__popcll(bal));

  int r = rank[(size_t)n * PTOT + i];  // stable permutation
  float gm = dec_f(gmax[n]);
  int li = label[(size_t)n * PTOT + i];
  const float* bp = boxes + ((size_t)n * PTOT + i) * 4;
  float b0 = bp[0], b1 = bp[1], b2 = bp[2], b3 = bp[3];
  float off = (float)li * (gm + 1.0f);
  float q0 = b0 + off, q1 = b1 + off, q2 = b2 + off, q3 = b3 + off;
  float area = (q2 - q0) * (q3 - q1);   // area from SHIFTED coords (matches reference)

  size_t d = (size_t)n * PTOT + (size_t)r;
  s_score[d] = v;
  s_label[d] = li;
  float* sb = s_box + d * 4;  sb[0] = b0; sb[1] = b1; sb[2] = b2; sb[3] = b3;
  float* sq = s_sbox + d * 4; sq[0] = q0; sq[1] = q1; sq[2] = q2; sq[3] = q3;
  s_area[d] = area;
  int pos = atomicAdd(&cursor[n * NCLS + li], 1);
  bidx[(size_t)n * PTOT + pos] = r;
}

// ---------------- sparse pair IoU -> edge list; LDS box tiles, dynamic slab distance
__global__ __launch_bounds__(256) void k_pairs(
    const float* __restrict__ s_sbox, const float* __restrict__ s_area,
    const int* __restrict__ bstart, const int* __restrict__ bidx,
    const unsigned* __restrict__ gmax, const unsigned* __restrict__ gmin,
    uint32_t* __restrict__ eb, int* __restrict__ ecnt, uint64_t* __restrict__ flags)
{
  int n = blockIdx.z, L = blockIdx.x, d = blockIdx.y;
  int L2 = L + d;
  if (L2 >= NCLS) return;
  if (d > 0) {
    // slabs [off+m, off+g] at distance d(g+1) can't overlap when d(g+1) > g-m
    // (+1.0f slack makes float rounding err only toward extra exact work)
    float gm = dec_f(gmax[n]), gmn = dec_f(gmin[n]);
    if ((float)d * (gm + 1.0f) > (gm - gmn) + 1.0f) return;
  }
  const int* bs = bstart + n * (NCLS + 1);
  int a0 = bs[L], na = bs[L + 1] - a0;
  int b0 = bs[L2], nb = bs[L2 + 1] - b0;
  if (na == 0 || nb == 0) return;
  const int* ba = bidx + (size_t)n * PTOT + a0;
  const int* bb = bidx + (size_t)n * PTOT + b0;
  const float4* SB = (const float4*)(s_sbox + (size_t)n * PTOT * 4);
  const float* SA = s_area + (size_t)n * PTOT;

  __shared__ float4 lA[PTILE]; __shared__ float lAa[PTILE]; __shared__ int liA[PTILE];
  __shared__ float4 lB[PTILE]; __shared__ float lBa[PTILE]; __shared__ int liB[PTILE];
  int tid = threadIdx.x;

  for (int ub = 0; ub < na; ub += PTILE) {
    int ua = min(PTILE, na - ub);
    for (int i = tid; i < ua; i += 256) {        // stage A tile (gather once per box)
      int p = ba[ub + i];
      liA[i] = p; lA[i] = SB[p]; lAa[i] = SA[p];
    }
    for (int vb = 0; vb < nb; vb += PTILE) {
      int va = min(PTILE, nb - vb);
      for (int i = tid; i < va; i += 256) {      // stage B tile
        int p = bb[vb + i];
        liB[i] = p; lB[i] = SB[p]; lBa[i] = SA[p];
      }
      __syncthreads();
      for (int u = 0; u < ua; ++u) {
        float4 A = lA[u]; float aa = lAa[u]; int p = liA[u];   // LDS broadcast
        int vstart = 0;
        if (d == 0) { vstart = (ub + u) + 1 - vb; if (vstart < 0) vstart = 0; }
        for (int v = vstart + tid; v < va; v += 256) {
          float4 B = lB[v];
          float ww = fminf(A.z, B.z) - fmaxf(A.x, B.x);
          float hh = fminf(A.w, B.w) - fmaxf(A.y, B.y);
          if (ww <= 0.0f || hh <= 0.0f) continue;  // inter=0 -> iou=0 -> no edge (exact)
          float inter = ww * hh;
          float uni = fmaxf(aa + lBa[v] - inter, 1e-12f);
          if (inter / uni > NMS_THR_C) {           // identical arithmetic to reference
            uint32_t q = (uint32_t)liB[v];
            uint32_t i_ = min((uint32_t)p, q), j_ = max((uint32_t)p, q);
            int idx = atomicAdd(&ecnt[n], 1);
            if (idx < ECAP) eb[(size_t)n * ECAP + idx] = (i_ << 16) | j_;
            atomicOr((unsigned long long*)&flags[(size_t)n * NW + (i_ >> 6)], 1ull << (i_ & 63u));
          }
        }
      }
      __syncthreads();
    }
  }
}

// ---------------- greedy suppression: event-driven over edge list, LDS removed-bitmask
__global__ __launch_bounds__(64) void k_scan(
    const uint32_t* __restrict__ eb, const int* __restrict__ ecnt,
    const uint64_t* __restrict__ flags, const int* __restrict__ nvalid,
    uint64_t* __restrict__ keepw)
{
  __shared__ uint64_t Rm[NW];   // removed bitmask
  __shared__ uint64_t Fl[NW];   // rows-with-edges bitmap
  int n = blockIdx.x, l = threadIdx.x;
  int nv = nvalid[n];
  auto initw = [&](int w) -> uint64_t {
    int base = w * 64;
    if (nv <= base) return ~0ull;
    if (nv >= base + 64) return 0ull;
    return (~0ull) << (nv - base);
  };
  const uint64_t* fl = flags + (size_t)n * NW;
  uint64_t f0 = fl[l], f1 = fl[64 + l], f2 = (l < 4) ? fl[128 + l] : 0ull;
  Rm[l] = initw(l); Rm[64 + l] = initw(64 + l);
  if (l < 4) Rm[128 + l] = initw(128 + l);
  Fl[l] = f0; Fl[64 + l] = f1;
  if (l < 4) Fl[128 + l] = f2;
  uint64_t nzc0 = __ballot(f0 != 0ull);                 // chunks 0..63 with events
  uint64_t nzc1 = __ballot(f1 != 0ull);                 // 64..127
  uint64_t nzc2 = __ballot((l < 4) && (f2 != 0ull));    // 128..131
  int cnt = ecnt[n]; if (cnt > ECAP) cnt = ECAP;
  const uint32_t* E = eb + (size_t)n * ECAP;
  uint32_t Er[16];
#pragma unroll
  for (int s = 0; s < 16; ++s) {
    int k = s * 64 + l;
    Er[s] = (k < cnt) ? E[k] : 0xFFFFFFFFu;             // sentinel never matches
  }
  // single wave: LDS ops ordered via lgkmcnt; no barriers needed
  for (int seg = 0; seg < 3; ++seg) {
    uint64_t bm = (seg == 0) ? nzc0 : (seg == 1) ? nzc1 : nzc2;
    int cb = seg * 64;
    while (bm) {
      int c = cb + __builtin_ctzll(bm); bm &= bm - 1;
      uint64_t F = Fl[c];                               // uniform broadcast read
      while (F) {
        int b = __builtin_ctzll(F); F &= F - 1;
        uint64_t cur = Rm[c];                           // fresh (in-chunk updates visible)
        if ((cur >> b) & 1ull) continue;                // row already suppressed
        uint32_t i = (uint32_t)(c * 64 + b);
        // apply row i: all lanes scan their register edges for i-matches
#pragma unroll
        for (int s = 0; s < 16; ++s) {
          uint32_t e = Er[s];
          if ((e >> 16) == i) {
            uint32_t j = e & 0xFFFFu;                   // j > i always (k_pairs)
            atomicOr((unsigned long long*)&Rm[j >> 6], 1ull << (j & 63u));
          }
        }
        if (cnt > ERCAP) {                              // emergency overflow path
          for (int k = ERCAP + l; k < cnt; k += 64) {
            uint32_t e = E[k];
            if ((e >> 16) == i) {
              uint32_t j = e & 0xFFFFu;
              atomicOr((unsigned long long*)&Rm[j >> 6], 1ull << (j & 63u));
            }
          }
        }
      }
    }
  }
  keepw[(size_t)n * NW + l] = ~Rm[l];
  keepw[(size_t)n * NW + 64 + l] = ~Rm[64 + l];
  if (l < 4) keepw[(size_t)n * NW + 128 + l] = ~Rm[128 + l];
}

// ---------------- finalize outputs
__global__ __launch_bounds__(256) void k_final(
    const float* __restrict__ s_score, const int* __restrict__ s_label,
    const float* __restrict__ s_box, const uint64_t* __restrict__ keepw,
    float* __restrict__ out)
{
  int t = blockIdx.x * 256 + threadIdx.x;
  if (t >= NIMG * PTOT) return;
  int n = t / PTOT, p = t - n * PTOT;
  uint64_t w = keepw[(size_t)n * NW + (p >> 6)];
  float k = (float)((w >> (p & 63)) & 1ull);
  float* dets = out;
  float* lab  = out + (size_t)NIMG * PTOT * 5;
  float* kp   = out + (size_t)NIMG * PTOT * 6;
  const float* bp = s_box + (size_t)t * 4;
  float* dp = dets + (size_t)t * 5;
  dp[0] = bp[0] * k; dp[1] = bp[1] * k; dp[2] = bp[2] * k; dp[3] = bp[3] * k;
  dp[4] = s_score[t] * k;
  lab[t] = (float)s_label[t];
  kp[t]  = k;
}

extern "C" void kernel_launch(void* const* d_in, const int* in_sizes, int n_in,
                              void* d_out, int out_size, void* d_ws, size_t ws_size,
                              hipStream_t stream)
{
  const float* cls0 = (const float*)d_in[0];
  const float* cls1 = (const float*)d_in[1];
  const float* cls2 = (const float*)d_in[2];
  const float* reg0 = (const float*)d_in[3];
  const float* reg1 = (const float*)d_in[4];
  const float* reg2 = (const float*)d_in[5];
  const float* obj0 = (const float*)d_in[6];
  const float* obj1 = (const float*)d_in[7];
  const float* obj2 = (const float*)d_in[8];

  char* w = (char*)d_ws;
  uint64_t* keepw = (uint64_t*)w; w += (size_t)NIMG * NW * 8;          // 4,224 B
  uint64_t* flags = (uint64_t*)w; w += (size_t)NIMG * NW * 8;          // 4,224 B
  float* score = (float*)w;       w += (size_t)NIMG * PTOT * 4;
  int*   label = (int*)w;         w += (size_t)NIMG * PTOT * 4;
  float* boxes = (float*)w;       w += (size_t)NIMG * PTOT * 16;
  float* ss = (float*)w;          w += (size_t)NIMG * PTOT * 4;
  int*   sl = (int*)w;            w += (size_t)NIMG * PTOT * 4;
  float* sb = (float*)w;          w += (size_t)NIMG * PTOT * 16;
  float* sq = (float*)w;          w += (size_t)NIMG * PTOT * 16;
  float* sa = (float*)w;          w += (size_t)NIMG * PTOT * 4;
  unsigned* gmax = (unsigned*)w;  w += 256;
  unsigned* gmin = (unsigned*)w;  w += 256;
  int* nvalid = (int*)w;          w += 256;
  int* rank = (int*)w;            w += (size_t)NIMG * PTOT * 4;
  int* lhist = (int*)w;           w += (size_t)NIMG * NCLS * 4;        // 1,280 B
  int* bstart = (int*)w;          w += (size_t)NIMG * (NCLS + 1) * 4;  // 1,296 B
  int* cursor = (int*)w;          w += (size_t)NIMG * NCLS * 4;
  int* bidx = (int*)w;            w += (size_t)NIMG * PTOT * 4;
  uint32_t* eb = (uint32_t*)w;    w += (size_t)NIMG * ECAP * 4;        // 1 MB
  int* ecnt = (int*)w;            w += 256;

  k_init<<<dim3(4), dim3(256), 0, stream>>>(gmax, gmin, flags, nvalid, lhist, ecnt);
  k_decode<<<dim3((NIMG * PTOT * 4) / 256), dim3(256), 0, stream>>>(
      cls0, cls1, cls2, reg0, reg1, reg2, obj0, obj1, obj2,
      score, label, boxes, gmax, gmin, lhist);
  k_sort<<<dim3(NIMG), dim3(SORT_T), 0, stream>>>(score, rank, lhist, bstart, cursor);
  k_scatter<<<dim3((PTOT + 255) / 256, NIMG), dim3(256), 0, stream>>>(
      score, label, boxes, gmax, rank, nvalid, ss, sl, sb, sq, sa, cursor, bidx);
  k_pairs<<<dim3(NCLS, DMAX + 1, NIMG), dim3(256), 0, stream>>>(
      sq, sa, bstart, bidx, gmax, gmin, eb, ecnt, flags);
  k_scan<<<dim3(NIMG), dim3(64), 0, stream>>>(eb, ecnt, flags, nvalid, keepw);
  k_final<<<dim3((NIMG * PTOT + 255) / 256), dim3(256), 0, stream>>>(
      ss, sl, sb, keepw, (float*)d_out);
}